// Round 1
// 665.279 us; speedup vs baseline: 1.1660x; 1.1660x over previous
//
#include <hip/hip_runtime.h>

typedef unsigned short u16;
typedef unsigned int u32;

typedef __attribute__((ext_vector_type(8))) short short8;
typedef __attribute__((ext_vector_type(4))) float float4v;

__device__ __forceinline__ float bf2f(u16 u) { return __uint_as_float(((u32)u) << 16); }
__device__ __forceinline__ u16 f2bf(float f) {
    u32 x = __float_as_uint(f);
    return (u16)((x + 0x7fffu + ((x >> 16) & 1u)) >> 16);
}
__device__ __forceinline__ float sigmoidf_(float x) { return 1.0f / (1.0f + expf(-x)); }

#define B_ 128
#define T_ 20
#define VISN 196
#define VISD 512
#define EMB 256
#define HID 512
#define VOC 10000
#define VOCP 10112   /* padded to 79*128 */
#define NBLK 64      /* recurrence grid: 2 rowgroups x 32 colgroups */

// ---------------------------------------------------------------------------
// fused weight conversion f32 -> bf16 (+ zero-pad Wo/bo to VOCP, zero flags)
// one element per thread; segments by flat gid.
// ---------------------------------------------------------------------------
__global__ __launch_bounds__(256) void conv_all(
    const float* __restrict__ Wih, const float* __restrict__ Whh,
    const float* __restrict__ Wo,  const float* __restrict__ Winh,
    const float* __restrict__ Winc, const float* __restrict__ bih,
    const float* __restrict__ bhh, const float* __restrict__ bo,
    u16* __restrict__ cWih, u16* __restrict__ cWhh, u16* __restrict__ cWo,
    u16* __restrict__ cWinit, u16* __restrict__ cbih, u16* __restrict__ cbhh,
    u16* __restrict__ cbo, int* __restrict__ flags) {
    const int e0 = 1572864, e1 = 2621440, e2 = 7798784, e3 = 8060928,
              e4 = 8323072, e5 = 8325120, e6 = 8327168, e7 = 8337280;
    int gid = blockIdx.x * 256 + threadIdx.x;
    if (gid < NBLK) flags[gid] = 0;
    if (gid >= e7) return;
    if (gid < e0) { cWih[gid] = f2bf(Wih[gid]); }
    else if (gid < e1) { int l = gid - e0; cWhh[l] = f2bf(Whh[l]); }
    else if (gid < e2) {
        int l = gid - e1; int row = l >> 9, col = l & 511;
        cWo[l] = (row < VOC) ? f2bf(Wo[(size_t)row * 512 + col]) : (u16)0;
    }
    else if (gid < e3) { int l = gid - e2; cWinit[l] = f2bf(Winh[l]); }
    else if (gid < e4) { int l = gid - e3; cWinit[262144 + l] = f2bf(Winc[l]); }
    else if (gid < e5) { int l = gid - e4; cbih[l] = f2bf(bih[l]); }
    else if (gid < e6) { int l = gid - e5; cbhh[l] = f2bf(bhh[l]); }
    else { int l = gid - e6; cbo[l] = (l < VOC) ? f2bf(bo[l]) : (u16)0; }
}

// ---------------------------------------------------------------------------
// att: alpha[b,n] = softmax_n(features[b,n,:]·Wv). h-term of the logit is
// constant over n -> softmax-invariant -> dropped. One block per b.
// ---------------------------------------------------------------------------
__global__ __launch_bounds__(256) void att_kernel(const float* __restrict__ feat,
                                                  const float* __restrict__ Wv,
                                                  float* __restrict__ alpha) {
    __shared__ float wv[512];
    __shared__ float att[VISN];
    __shared__ float red[256];
    int b = blockIdx.x, tid = threadIdx.x;
    wv[tid] = Wv[tid];
    wv[tid + 256] = Wv[tid + 256];
    __syncthreads();
    int w = tid >> 6, lane = tid & 63;
    for (int n = w; n < VISN; n += 4) {
        const float4* fp = (const float4*)(feat + ((size_t)b * VISN + n) * VISD) + lane * 2;
        float4 a = fp[0], c = fp[1];
        const float* wp = wv + lane * 8;
        float s = a.x * wp[0] + a.y * wp[1] + a.z * wp[2] + a.w * wp[3]
                + c.x * wp[4] + c.y * wp[5] + c.z * wp[6] + c.w * wp[7];
        #pragma unroll
        for (int off = 32; off; off >>= 1) s += __shfl_down(s, off);
        if (lane == 0) att[n] = s;
    }
    __syncthreads();
    float m = -1e30f;
    for (int i = tid; i < VISN; i += 256) m = fmaxf(m, att[i]);
    red[tid] = m; __syncthreads();
    for (int s = 128; s; s >>= 1) { if (tid < s) red[tid] = fmaxf(red[tid], red[tid + s]); __syncthreads(); }
    m = red[0]; __syncthreads();
    float sum = 0.f;
    for (int i = tid; i < VISN; i += 256) { float e = expf(att[i] - m); att[i] = e; sum += e; }
    red[tid] = sum; __syncthreads();
    for (int s = 128; s; s >>= 1) { if (tid < s) red[tid] += red[tid + s]; __syncthreads(); }
    float inv = 1.0f / red[0]; __syncthreads();
    for (int i = tid; i < VISN; i += 256) alpha[b * VISN + i] = att[i] * inv;
}

// ---------------------------------------------------------------------------
// ctx/fbar: fbar = mean_n feat, ctx = sum_n alpha*feat. grid (2 vslices, 128 b)
// ---------------------------------------------------------------------------
__global__ __launch_bounds__(256) void ctx_fbar(const float* __restrict__ feat,
                                                const float* __restrict__ alpha,
                                                u16* __restrict__ fbar_bf,
                                                u16* __restrict__ ctx_bf) {
    __shared__ float al[VISN];
    int b = blockIdx.y, tid = threadIdx.x;
    int v = blockIdx.x * 256 + tid;
    if (tid < VISN) al[tid] = alpha[b * VISN + tid];
    __syncthreads();
    float accf = 0.f, accc = 0.f;
    const float* fp = feat + (size_t)b * VISN * VISD + v;
    #pragma unroll 4
    for (int n = 0; n < VISN; n++) {
        float f = fp[(size_t)n * VISD];
        accf += f;
        accc += al[n] * f;
    }
    fbar_bf[b * VISD + v] = f2bf(accf / (float)VISN);
    ctx_bf[b * VISD + v] = f2bf(accc);
}

// gather embeddings, time-major r = t*B + b
__global__ void gather_emb(const int* __restrict__ captions, const float* __restrict__ table,
                           u16* __restrict__ Ebf) {
    int r = blockIdx.x;
    int t = r >> 7, b = r & 127;
    int idx = captions[b * T_ + t];
    Ebf[(size_t)r * EMB + threadIdx.x] = f2bf(table[(size_t)idx * EMB + threadIdx.x]);
}

// ---------------------------------------------------------------------------
// bf16 MFMA GEMM, 64x64 tile, BK=32. C = A[M,K]·B[N,K]^T + biases + addA.
// mode 0: write bf16 Cbf; mode 1: write f32 Cf; mode 2: h0c0 split
// (col<512 -> Cbf=h bf16 at grow*512+col, else Cf=c f32 at grow*512+col-512).
// addA (f32) indexed [(grow & rowmask)*ldc + gcol].
// ---------------------------------------------------------------------------
__global__ __launch_bounds__(256) void gemm_bt(const u16* __restrict__ A, int lda,
                                               const u16* __restrict__ Bm, int ldb,
                                               int M, int N, int K,
                                               const u16* __restrict__ bias0,
                                               const u16* __restrict__ bias1,
                                               const float* __restrict__ addA, int rowmask,
                                               float* __restrict__ Cf,
                                               u16* __restrict__ Cbf, int ldc, int mode) {
    __shared__ u16 As[64 * 32];
    __shared__ u16 Bs[64 * 32];
    int tid = threadIdx.x;
    int n0 = blockIdx.x * 64, m0 = blockIdx.y * 64;
    int w = tid >> 6, lane = tid & 63;
    int wm = (w & 1) * 32, wn = (w >> 1) * 32;
    int mrow = lane & 15, quad = lane >> 4;
    float4v acc[2][2] = {};
    int lr = tid >> 2;
    int lc = (tid & 3) * 8;
    for (int k0 = 0; k0 < K; k0 += 32) {
        *(uint4*)(&As[lr * 32 + lc]) = *(const uint4*)(A + (size_t)(m0 + lr) * lda + k0 + lc);
        *(uint4*)(&Bs[lr * 32 + lc]) = *(const uint4*)(Bm + (size_t)(n0 + lr) * ldb + k0 + lc);
        __syncthreads();
        short8 afrag[2], bfrag[2];
        #pragma unroll
        for (int i = 0; i < 2; i++)
            afrag[i] = *(const short8*)(&As[(wm + i * 16 + mrow) * 32 + quad * 8]);
        #pragma unroll
        for (int j = 0; j < 2; j++)
            bfrag[j] = *(const short8*)(&Bs[(wn + j * 16 + mrow) * 32 + quad * 8]);
        #pragma unroll
        for (int i = 0; i < 2; i++)
            #pragma unroll
            for (int j = 0; j < 2; j++)
                acc[i][j] = __builtin_amdgcn_mfma_f32_16x16x32_bf16(afrag[i], bfrag[j], acc[i][j], 0, 0, 0);
        __syncthreads();
    }
    #pragma unroll
    for (int i = 0; i < 2; i++) {
        #pragma unroll
        for (int j = 0; j < 2; j++) {
            #pragma unroll
            for (int r = 0; r < 4; r++) {
                int grow = m0 + wm + i * 16 + quad * 4 + r;
                int gcol = n0 + wn + j * 16 + mrow;
                float v = acc[i][j][r];
                if (bias0) v += bf2f(bias0[gcol]);
                if (bias1) v += bf2f(bias1[gcol]);
                if (addA) v += addA[(size_t)(grow & rowmask) * ldc + gcol];
                if (mode == 0) {
                    Cbf[(size_t)grow * ldc + gcol] = f2bf(v);
                } else if (mode == 1) {
                    Cf[(size_t)grow * ldc + gcol] = v;
                } else {  // mode 2: h0/c0 split
                    if (gcol < 512) Cbf[(size_t)grow * 512 + gcol] = f2bf(v);
                    else Cf[(size_t)grow * 512 + gcol - 512] = v;
                }
            }
        }
    }
}

// ---------------------------------------------------------------------------
// persistent fused recurrence, v2: 64 blocks = 2 rowgroups (64 batch rows) x
// 32 colgroups (64 gate cols = 4 gates x 16 h-cols). Key properties:
//   - each wave owns a 16-row strip: its MFMA A-fragments (h[16][512]) load
//     straight from global into 64 VGPRs -- no LDS staging, no K-loop barriers
//   - W_hh slice [64][512] LDS-resident (stride 520, bank-uniform b128 reads),
//     loaded once for all 20 steps
//   - block's gate cols are {g*512 + 16*cg + q}, local order lcol = g*16+q, so
//     acc[g][r] holds all four gates (i,f,g,o) of one (row,col) in ONE lane:
//     LSTM elementwise is lane-local (no Gt, no shuffles); c-state in 4 regs
//   - rowgroups are data-independent => two 32-block barrier domains with
//     per-block release flags + 32-lane parallel poll (no atomicAdd contention)
//   - gbase loads issued AFTER af loads (vmcnt retires in order => MFMAs wait
//     only on af; cold gbase drains under the MFMA phase)
// ---------------------------------------------------------------------------
__global__ __launch_bounds__(256, 1) void recurrence(
    const u16* __restrict__ Whh,      // [2048,512] bf16
    const float* __restrict__ gbase,  // [2560,2048] f32 (row = t*128+b)
    const float* __restrict__ c0,     // [128,512] f32
    u16* __restrict__ h_pp,           // [2][128*512] bf16, buf0 = h0
    u16* __restrict__ h_all,          // [2560,512] bf16
    int* __restrict__ flags) {        // [64] step counters, zeroed by conv_all
    __shared__ u16 Ws[64 * 520];      // padded stride (bank spread)
    int jb = blockIdx.x, tid = threadIdx.x;
    int rg = jb >> 5, cg = jb & 31;
    // load W_hh slice: local row lcol = g*16+q -> global row g*512 + 16*cg + q
    for (int idx = tid; idx < 64 * 64; idx += 256) {
        int lcol = idx >> 6, q8 = idx & 63;
        int grow = ((lcol >> 4) << 9) + (cg << 4) + (lcol & 15);
        *(uint4*)&Ws[lcol * 520 + q8 * 8] = *(const uint4*)&Whh[(size_t)grow * 512 + q8 * 8];
    }
    int w = tid >> 6, lane = tid & 63;
    int mrow = lane & 15, quad = lane >> 4;
    int rowA = (rg << 6) + (w << 4) + mrow;          // A-fragment row
    int rowC = (rg << 6) + (w << 4) + (quad << 2);   // C row base (+r)
    int colh = (cg << 4) + mrow;                     // owned h column
    float cst[4];
    #pragma unroll
    for (int r = 0; r < 4; r++) cst[r] = c0[(size_t)(rowC + r) * 512 + colh];
    __syncthreads();
    for (int t = 0; t < T_; t++) {
        const u16* hcur = h_pp + (t & 1) * (B_ * HID);
        u16* hnxt = h_pp + ((t + 1) & 1) * (B_ * HID);
        // issue all A-fragment loads first (the MFMA critical path)
        short8 af[16];
        #pragma unroll
        for (int ks = 0; ks < 16; ks++)
            af[ks] = *(const short8*)&hcur[(size_t)rowA * 512 + ks * 32 + quad * 8];
        // then the gbase addends (retire later; consumed in epilogue)
        float gb[4][4];
        #pragma unroll
        for (int g = 0; g < 4; g++)
            #pragma unroll
            for (int r = 0; r < 4; r++)
                gb[g][r] = gbase[(size_t)(t * B_ + rowC + r) * 2048 + (g << 9) + colh];
        float4v acc[4] = {};
        #pragma unroll
        for (int ks = 0; ks < 16; ks++) {
            #pragma unroll
            for (int g = 0; g < 4; g++) {
                short8 bf = *(const short8*)&Ws[((g << 4) + mrow) * 520 + ks * 32 + quad * 8];
                acc[g] = __builtin_amdgcn_mfma_f32_16x16x32_bf16(af[ks], bf, acc[g], 0, 0, 0);
            }
        }
        // lane-local LSTM elementwise (i,f,g,o all in this lane)
        #pragma unroll
        for (int r = 0; r < 4; r++) {
            float ig = sigmoidf_(acc[0][r] + gb[0][r]);
            float fg = sigmoidf_(acc[1][r] + gb[1][r]);
            float gg = tanhf(acc[2][r] + gb[2][r]);
            float og = sigmoidf_(acc[3][r] + gb[3][r]);
            float cn = fg * cst[r] + ig * gg;
            cst[r] = cn;
            u16 hv = f2bf(og * tanhf(cn));
            hnxt[(size_t)(rowC + r) * 512 + colh] = hv;
            h_all[(size_t)(t * B_ + rowC + r) * 512 + colh] = hv;
        }
        // barrier (per-rowgroup domain): release own flag, poll the 32 flags
        __syncthreads();
        if (tid == 0) {
            __threadfence();
            __hip_atomic_store(&flags[jb], t + 1, __ATOMIC_RELEASE, __HIP_MEMORY_SCOPE_AGENT);
        }
        if (tid < 32) {
            while (__hip_atomic_load(&flags[(rg << 5) + tid], __ATOMIC_ACQUIRE,
                                     __HIP_MEMORY_SCOPE_AGENT) <= t)
                __builtin_amdgcn_s_sleep(1);
            __threadfence();
        }
        __syncthreads();
    }
}

// ---------------------------------------------------------------------------
// logits GEMM, 128x128 tile, BK=32, 4 waves each 64x64 (4x4 of 16x16x32).
// A = h_all [2560,512], B = cWo [VOCP,512] (zero-padded). C f32 -> d_out
// second half, col-guarded, + bo.
// ---------------------------------------------------------------------------
__global__ __launch_bounds__(256) void gemm128(const u16* __restrict__ A,
                                               const u16* __restrict__ Bm,
                                               const u16* __restrict__ biasbf,
                                               float* __restrict__ C) {
    __shared__ u16 As[128 * 32];
    __shared__ u16 Bs[128 * 32];
    int tid = threadIdx.x;
    int n0 = blockIdx.x * 128, m0 = blockIdx.y * 128;
    int w = tid >> 6, lane = tid & 63;
    int wm = (w & 1) * 64, wn = (w >> 1) * 64;
    int mrow = lane & 15, quad = lane >> 4;
    float4v acc[4][4] = {};
    for (int k0 = 0; k0 < 512; k0 += 32) {
        #pragma unroll
        for (int q = 0; q < 2; q++) {
            int idx = tid * 2 + q;              // 0..511 uint4s per matrix
            int r = idx >> 2, cc = (idx & 3) * 8;
            *(uint4*)&As[r * 32 + cc] = *(const uint4*)&A[(size_t)(m0 + r) * 512 + k0 + cc];
            *(uint4*)&Bs[r * 32 + cc] = *(const uint4*)&Bm[(size_t)(n0 + r) * 512 + k0 + cc];
        }
        __syncthreads();
        short8 af[4], bfv[4];
        #pragma unroll
        for (int i = 0; i < 4; i++)
            af[i] = *(const short8*)&As[(wm + i * 16 + mrow) * 32 + quad * 8];
        #pragma unroll
        for (int jn = 0; jn < 4; jn++)
            bfv[jn] = *(const short8*)&Bs[(wn + jn * 16 + mrow) * 32 + quad * 8];
        #pragma unroll
        for (int i = 0; i < 4; i++)
            #pragma unroll
            for (int jn = 0; jn < 4; jn++)
                acc[i][jn] = __builtin_amdgcn_mfma_f32_16x16x32_bf16(af[i], bfv[jn], acc[i][jn], 0, 0, 0);
        __syncthreads();
    }
    #pragma unroll
    for (int i = 0; i < 4; i++) {
        #pragma unroll
        for (int jn = 0; jn < 4; jn++) {
            int gcol = n0 + wn + jn * 16 + mrow;
            if (gcol >= VOC) continue;
            float bias = bf2f(biasbf[gcol]);
            #pragma unroll
            for (int r = 0; r < 4; r++) {
                int grow = m0 + wm + i * 16 + quad * 4 + r;
                C[(size_t)grow * VOC + gcol] = acc[i][jn][r] + bias;
            }
        }
    }
}

// ---------------------------------------------------------------------------
// fused log_softmax + softmax over d_out rows (f32). Raw logits in 2nd half.
// ---------------------------------------------------------------------------
__global__ __launch_bounds__(256) void softmax_out(float* __restrict__ out) {
    __shared__ float red[256];
    int r = blockIdx.x, tid = threadIdx.x;
    const size_t HALF4 = (size_t)T_ * B_ * VOC / 4;  // in float4 units
    float4* outv = (float4*)out;
    float4* src = outv + HALF4 + (size_t)r * (VOC / 4);
    float4 lv[10];
    float m = -1e30f;
    #pragma unroll
    for (int jq = 0; jq < 10; jq++) {
        int i4 = tid + jq * 256;
        if (i4 < VOC / 4) {
            float4 v = src[i4];
            lv[jq] = v;
            m = fmaxf(m, fmaxf(fmaxf(v.x, v.y), fmaxf(v.z, v.w)));
        } else {
            lv[jq] = make_float4(-1e30f, -1e30f, -1e30f, -1e30f);
        }
    }
    red[tid] = m; __syncthreads();
    for (int s = 128; s; s >>= 1) { if (tid < s) red[tid] = fmaxf(red[tid], red[tid + s]); __syncthreads(); }
    m = red[0]; __syncthreads();
    float sum = 0.f;
    #pragma unroll
    for (int jq = 0; jq < 10; jq++)
        sum += expf(lv[jq].x - m) + expf(lv[jq].y - m) + expf(lv[jq].z - m) + expf(lv[jq].w - m);
    red[tid] = sum; __syncthreads();
    for (int s = 128; s; s >>= 1) { if (tid < s) red[tid] += red[tid + s]; __syncthreads(); }
    float logZ = m + logf(red[0]);
    float4* dls = outv + (size_t)r * (VOC / 4);
    #pragma unroll
    for (int jq = 0; jq < 10; jq++) {
        int i4 = tid + jq * 256;
        if (i4 < VOC / 4) {
            float4 v = lv[jq];
            float4 ls = make_float4(v.x - logZ, v.y - logZ, v.z - logZ, v.w - logZ);
            dls[i4] = ls;
            src[i4] = make_float4(expf(ls.x), expf(ls.y), expf(ls.z), expf(ls.w));
        }
    }
}

extern "C" void kernel_launch(void* const* d_in, const int* in_sizes, int n_in,
                              void* d_out, int out_size, void* d_ws, size_t ws_size,
                              hipStream_t stream) {
    const float* features = (const float*)d_in[0];
    const int* captions   = (const int*)d_in[1];
    const float* W_init_h = (const float*)d_in[2];
    const float* W_init_c = (const float*)d_in[3];
    const float* Wv       = (const float*)d_in[4];
    // d_in[5] bv, d_in[6] Wa, d_in[7] ba unused (softmax shift-invariance)
    const float* embed_t  = (const float*)d_in[8];
    const float* W_ih     = (const float*)d_in[9];
    const float* W_hh     = (const float*)d_in[10];
    const float* b_ih     = (const float*)d_in[11];
    const float* b_hh     = (const float*)d_in[12];
    const float* Wo       = (const float*)d_in[13];
    const float* bo       = (const float*)d_in[14];
    float* out = (float*)d_out;

    // workspace layout (~43.5 MB)
    char* base = (char*)d_ws;
    int*   flags   = (int*)(base + 0);            // [64] barrier flags
    float* alpha   = (float*)(base + 1024);
    u16*   fbar_bf = (u16*)(base + 103424);
    u16*   ctx_bf  = (u16*)(base + 234496);
    u16*   h_pp    = (u16*)(base + 365568);       // 2 x 128*512 bf16
    float* c_f32   = (float*)(base + 627712);
    float* gconst  = (float*)(base + 889856);     // [128,2048] f32
    u16*   Ebf     = (u16*)(base + 1938432);      // [2560,256] bf16
    float* gbase   = (float*)(base + 3249152);    // [2560,2048] f32
    u16*   h_all   = (u16*)(base + 24220672);     // [2560,512] bf16
    u16*   cWih    = (u16*)(base + 26842112);     // [2048,768] bf16
    u16*   cWhh    = (u16*)(base + 29987840);     // [2048,512]
    u16*   cWo     = (u16*)(base + 32084992);     // [VOCP,512] padded
    u16*   cWinit  = (u16*)(base + 42439680);     // [1024,512] (Winh;Winc)
    u16*   cbih    = (u16*)(base + 43488256);
    u16*   cbhh    = (u16*)(base + 43492352);
    u16*   cbo     = (u16*)(base + 43496448);     // [VOCP] padded

    // 1) weight conversion (+ flag zero)
    conv_all<<<32568, 256, 0, stream>>>(W_ih, W_hh, Wo, W_init_h, W_init_c,
                                        b_ih, b_hh, bo,
                                        cWih, cWhh, cWo, cWinit, cbih, cbhh, cbo, flags);
    // 2) attention weights + context/mean features
    att_kernel<<<B_, 256, 0, stream>>>(features, Wv, alpha);
    ctx_fbar<<<dim3(2, B_), 256, 0, stream>>>(features, alpha, fbar_bf, ctx_bf);
    // 3) embeddings (time-major)
    gather_emb<<<T_ * B_, 256, 0, stream>>>(captions, embed_t, Ebf);
    // 4) h0 | c0 = fbar @ [Winh; Winc]^T   (split epilogue)
    gemm_bt<<<dim3(16, 2), 256, 0, stream>>>(
        fbar_bf, 512, cWinit, 512, B_, 1024, 512,
        nullptr, nullptr, nullptr, -1, c_f32, h_pp, 1024, 2);
    // 5) gconst = ctx @ W_ih[:, :512]^T + b_ih + b_hh   [128,2048] f32
    gemm_bt<<<dim3(32, 2), 256, 0, stream>>>(
        ctx_bf, 512, cWih, 768, B_, 2048, 512,
        cbih, cbhh, nullptr, -1, gconst, nullptr, 2048, 1);
    // 6) gbase = E @ W_ih[:, 512:768]^T + gconst[b]   [2560,2048] f32
    gemm_bt<<<dim3(32, 40), 256, 0, stream>>>(
        Ebf, 256, cWih + 512, 768, T_ * B_, 2048, 256,
        nullptr, nullptr, gconst, 127, gbase, nullptr, 2048, 1);
    // 7) fused 20-step LSTM recurrence (single persistent launch)
    recurrence<<<NBLK, 256, 0, stream>>>(cWhh, gbase, c_f32, h_pp, h_all, flags);
    // 8) logits = h_all @ Wo^T + bo -> f32 raw into d_out's second half
    gemm128<<<dim3(VOCP / 128, (T_ * B_) / 128), 256, 0, stream>>>(
        h_all, cWo, cbo, out + (size_t)T_ * B_ * VOC);
    // 9) fused log_softmax + softmax in place
    softmax_out<<<T_ * B_, 256, 0, stream>>>(out);
}

// Round 2
// 614.140 us; speedup vs baseline: 1.2631x; 1.0833x over previous
//
#include <hip/hip_runtime.h>

typedef unsigned short u16;
typedef unsigned int u32;
typedef unsigned long long u64;

typedef __attribute__((ext_vector_type(8))) short short8;
typedef __attribute__((ext_vector_type(4))) float float4v;

__device__ __forceinline__ float bf2f(u16 u) { return __uint_as_float(((u32)u) << 16); }
__device__ __forceinline__ u16 f2bf(float f) {
    u32 x = __float_as_uint(f);
    return (u16)((x + 0x7fffu + ((x >> 16) & 1u)) >> 16);
}
__device__ __forceinline__ float sigmoidf_(float x) { return 1.0f / (1.0f + expf(-x)); }

#define B_ 128
#define T_ 20
#define VISN 196
#define VISD 512
#define EMB 256
#define HID 512
#define VOC 10000
#define VOCP 10112   /* padded to 79*128 */
#define NBLK 64      /* recurrence grid: 2 rowgroups x 32 colgroups */

// ---------------------------------------------------------------------------
// fused weight conversion f32 -> bf16 (+ zero-pad Wo/bo to VOCP, zero flags)
// one element per thread; segments by flat gid.
// ---------------------------------------------------------------------------
__global__ __launch_bounds__(256) void conv_all(
    const float* __restrict__ Wih, const float* __restrict__ Whh,
    const float* __restrict__ Wo,  const float* __restrict__ Winh,
    const float* __restrict__ Winc, const float* __restrict__ bih,
    const float* __restrict__ bhh, const float* __restrict__ bo,
    u16* __restrict__ cWih, u16* __restrict__ cWhh, u16* __restrict__ cWo,
    u16* __restrict__ cWinit, u16* __restrict__ cbih, u16* __restrict__ cbhh,
    u16* __restrict__ cbo, int* __restrict__ flags) {
    const int e0 = 1572864, e1 = 2621440, e2 = 7798784, e3 = 8060928,
              e4 = 8323072, e5 = 8325120, e6 = 8327168, e7 = 8337280;
    int gid = blockIdx.x * 256 + threadIdx.x;
    if (gid < NBLK) flags[gid] = 0;
    if (gid >= e7) return;
    if (gid < e0) { cWih[gid] = f2bf(Wih[gid]); }
    else if (gid < e1) { int l = gid - e0; cWhh[l] = f2bf(Whh[l]); }
    else if (gid < e2) {
        int l = gid - e1; int row = l >> 9, col = l & 511;
        cWo[l] = (row < VOC) ? f2bf(Wo[(size_t)row * 512 + col]) : (u16)0;
    }
    else if (gid < e3) { int l = gid - e2; cWinit[l] = f2bf(Winh[l]); }
    else if (gid < e4) { int l = gid - e3; cWinit[262144 + l] = f2bf(Winc[l]); }
    else if (gid < e5) { int l = gid - e4; cbih[l] = f2bf(bih[l]); }
    else if (gid < e6) { int l = gid - e5; cbhh[l] = f2bf(bhh[l]); }
    else { int l = gid - e6; cbo[l] = (l < VOC) ? f2bf(bo[l]) : (u16)0; }
}

// ---------------------------------------------------------------------------
// att: alpha[b,n] = softmax_n(features[b,n,:]·Wv). h-term of the logit is
// constant over n -> softmax-invariant -> dropped. One block per b.
// ---------------------------------------------------------------------------
__global__ __launch_bounds__(256) void att_kernel(const float* __restrict__ feat,
                                                  const float* __restrict__ Wv,
                                                  float* __restrict__ alpha) {
    __shared__ float wv[512];
    __shared__ float att[VISN];
    __shared__ float red[256];
    int b = blockIdx.x, tid = threadIdx.x;
    wv[tid] = Wv[tid];
    wv[tid + 256] = Wv[tid + 256];
    __syncthreads();
    int w = tid >> 6, lane = tid & 63;
    for (int n = w; n < VISN; n += 4) {
        const float4* fp = (const float4*)(feat + ((size_t)b * VISN + n) * VISD) + lane * 2;
        float4 a = fp[0], c = fp[1];
        const float* wp = wv + lane * 8;
        float s = a.x * wp[0] + a.y * wp[1] + a.z * wp[2] + a.w * wp[3]
                + c.x * wp[4] + c.y * wp[5] + c.z * wp[6] + c.w * wp[7];
        #pragma unroll
        for (int off = 32; off; off >>= 1) s += __shfl_down(s, off);
        if (lane == 0) att[n] = s;
    }
    __syncthreads();
    float m = -1e30f;
    for (int i = tid; i < VISN; i += 256) m = fmaxf(m, att[i]);
    red[tid] = m; __syncthreads();
    for (int s = 128; s; s >>= 1) { if (tid < s) red[tid] = fmaxf(red[tid], red[tid + s]); __syncthreads(); }
    m = red[0]; __syncthreads();
    float sum = 0.f;
    for (int i = tid; i < VISN; i += 256) { float e = expf(att[i] - m); att[i] = e; sum += e; }
    red[tid] = sum; __syncthreads();
    for (int s = 128; s; s >>= 1) { if (tid < s) red[tid] += red[tid + s]; __syncthreads(); }
    float inv = 1.0f / red[0]; __syncthreads();
    for (int i = tid; i < VISN; i += 256) alpha[b * VISN + i] = att[i] * inv;
}

// ---------------------------------------------------------------------------
// ctx/fbar: fbar = mean_n feat, ctx = sum_n alpha*feat. grid (2 vslices, 128 b)
// ---------------------------------------------------------------------------
__global__ __launch_bounds__(256) void ctx_fbar(const float* __restrict__ feat,
                                                const float* __restrict__ alpha,
                                                u16* __restrict__ fbar_bf,
                                                u16* __restrict__ ctx_bf) {
    __shared__ float al[VISN];
    int b = blockIdx.y, tid = threadIdx.x;
    int v = blockIdx.x * 256 + tid;
    if (tid < VISN) al[tid] = alpha[b * VISN + tid];
    __syncthreads();
    float accf = 0.f, accc = 0.f;
    const float* fp = feat + (size_t)b * VISN * VISD + v;
    #pragma unroll 4
    for (int n = 0; n < VISN; n++) {
        float f = fp[(size_t)n * VISD];
        accf += f;
        accc += al[n] * f;
    }
    fbar_bf[b * VISD + v] = f2bf(accf / (float)VISN);
    ctx_bf[b * VISD + v] = f2bf(accc);
}

// gather embeddings, time-major r = t*B + b
__global__ void gather_emb(const int* __restrict__ captions, const float* __restrict__ table,
                           u16* __restrict__ Ebf) {
    int r = blockIdx.x;
    int t = r >> 7, b = r & 127;
    int idx = captions[b * T_ + t];
    Ebf[(size_t)r * EMB + threadIdx.x] = f2bf(table[(size_t)idx * EMB + threadIdx.x]);
}

// ---------------------------------------------------------------------------
// bf16 MFMA GEMM, 64x64 tile, BK=32. C = A[M,K]·B[N,K]^T + biases + addA.
// mode 0: write bf16 Cbf; mode 1: write f32 Cf; mode 2: h0c0 split
// (col<512 -> Cbf=h bf16 at grow*512+col, else Cf=c f32 at grow*512+col-512).
// addA (f32) indexed [(grow & rowmask)*ldc + gcol].
// ---------------------------------------------------------------------------
__global__ __launch_bounds__(256) void gemm_bt(const u16* __restrict__ A, int lda,
                                               const u16* __restrict__ Bm, int ldb,
                                               int M, int N, int K,
                                               const u16* __restrict__ bias0,
                                               const u16* __restrict__ bias1,
                                               const float* __restrict__ addA, int rowmask,
                                               float* __restrict__ Cf,
                                               u16* __restrict__ Cbf, int ldc, int mode) {
    __shared__ u16 As[64 * 32];
    __shared__ u16 Bs[64 * 32];
    int tid = threadIdx.x;
    int n0 = blockIdx.x * 64, m0 = blockIdx.y * 64;
    int w = tid >> 6, lane = tid & 63;
    int wm = (w & 1) * 32, wn = (w >> 1) * 32;
    int mrow = lane & 15, quad = lane >> 4;
    float4v acc[2][2] = {};
    int lr = tid >> 2;
    int lc = (tid & 3) * 8;
    for (int k0 = 0; k0 < K; k0 += 32) {
        *(uint4*)(&As[lr * 32 + lc]) = *(const uint4*)(A + (size_t)(m0 + lr) * lda + k0 + lc);
        *(uint4*)(&Bs[lr * 32 + lc]) = *(const uint4*)(Bm + (size_t)(n0 + lr) * ldb + k0 + lc);
        __syncthreads();
        short8 afrag[2], bfrag[2];
        #pragma unroll
        for (int i = 0; i < 2; i++)
            afrag[i] = *(const short8*)(&As[(wm + i * 16 + mrow) * 32 + quad * 8]);
        #pragma unroll
        for (int j = 0; j < 2; j++)
            bfrag[j] = *(const short8*)(&Bs[(wn + j * 16 + mrow) * 32 + quad * 8]);
        #pragma unroll
        for (int i = 0; i < 2; i++)
            #pragma unroll
            for (int j = 0; j < 2; j++)
                acc[i][j] = __builtin_amdgcn_mfma_f32_16x16x32_bf16(afrag[i], bfrag[j], acc[i][j], 0, 0, 0);
        __syncthreads();
    }
    #pragma unroll
    for (int i = 0; i < 2; i++) {
        #pragma unroll
        for (int j = 0; j < 2; j++) {
            #pragma unroll
            for (int r = 0; r < 4; r++) {
                int grow = m0 + wm + i * 16 + quad * 4 + r;
                int gcol = n0 + wn + j * 16 + mrow;
                float v = acc[i][j][r];
                if (bias0) v += bf2f(bias0[gcol]);
                if (bias1) v += bf2f(bias1[gcol]);
                if (addA) v += addA[(size_t)(grow & rowmask) * ldc + gcol];
                if (mode == 0) {
                    Cbf[(size_t)grow * ldc + gcol] = f2bf(v);
                } else if (mode == 1) {
                    Cf[(size_t)grow * ldc + gcol] = v;
                } else {  // mode 2: h0/c0 split
                    if (gcol < 512) Cbf[(size_t)grow * 512 + gcol] = f2bf(v);
                    else Cf[(size_t)grow * 512 + gcol - 512] = v;
                }
            }
        }
    }
}

// ---------------------------------------------------------------------------
// persistent fused recurrence, v3: 64 blocks = 2 rowgroups x 32 colgroups.
// v2 -> v3: all cross-block communication (h ping-pong, flags) now uses
// RELAXED agent-scope atomics (sc1 cache-bypassing loads/stores to the
// coherence point) instead of threadfence/acquire cache maintenance:
//   - release = s_waitcnt vmcnt(0) + relaxed flag store (no L2 writeback)
//   - acquire = relaxed flag poll (no L1/L2 invalidate -> gbase/Whh stay
//     warm in L2 across all 20 steps)
//   - barrier moved to loop HEAD; gbase loads for step t issue before the
//     poll and drain under the barrier wait
//   - h_all writes stay plain/cached (consumed only after kernel end)
// Safety (buffer parity): block A enters step t+1 only after every peer
// released t+1, which happens only after that peer's step-t reads retired
// (vmcnt(0) precedes the flag store) -> writes to buf[t&1] never race
// peer reads of it.
// ---------------------------------------------------------------------------
__global__ __launch_bounds__(256, 1) void recurrence(
    const u16* __restrict__ Whh,      // [2048,512] bf16
    const float* __restrict__ gbase,  // [2560,2048] f32 (row = t*128+b)
    const float* __restrict__ c0,     // [128,512] f32
    u16* __restrict__ h_pp,           // [2][128*512] bf16, buf0 = h0
    u16* __restrict__ h_all,          // [2560,512] bf16
    int* __restrict__ flags) {        // [64] step counters, zeroed by conv_all
    __shared__ u16 Ws[64 * 520];      // padded stride (bank spread)
    int jb = blockIdx.x, tid = threadIdx.x;
    int rg = jb >> 5, cg = jb & 31;
    // load W_hh slice: local row lcol = g*16+q -> global row g*512 + 16*cg + q
    for (int idx = tid; idx < 64 * 64; idx += 256) {
        int lcol = idx >> 6, q8 = idx & 63;
        int grow = ((lcol >> 4) << 9) + (cg << 4) + (lcol & 15);
        *(uint4*)&Ws[lcol * 520 + q8 * 8] = *(const uint4*)&Whh[(size_t)grow * 512 + q8 * 8];
    }
    int w = tid >> 6, lane = tid & 63;
    int mrow = lane & 15, quad = lane >> 4;
    int rowA = (rg << 6) + (w << 4) + mrow;          // A-fragment row
    int rowC = (rg << 6) + (w << 4) + (quad << 2);   // C row base (+r)
    int colh = (cg << 4) + mrow;                     // owned h column
    float cst[4];
    #pragma unroll
    for (int r = 0; r < 4; r++) cst[r] = c0[(size_t)(rowC + r) * 512 + colh];
    __syncthreads();
    for (int t = 0; t < T_; t++) {
        const u16* hcur = h_pp + (t & 1) * (B_ * HID);
        u16* hnxt = h_pp + ((t + 1) & 1) * (B_ * HID);
        // gbase addends for THIS step: plain cached loads issued before the
        // poll so they drain under the barrier wait (no race: gbase is
        // written by an earlier kernel)
        float gb[4][4];
        #pragma unroll
        for (int g = 0; g < 4; g++)
            #pragma unroll
            for (int r = 0; r < 4; r++)
                gb[g][r] = gbase[(size_t)(t * B_ + rowC + r) * 2048 + (g << 9) + colh];
        // barrier-at-head: wait for all peers in rowgroup to release step t
        if (t > 0) {
            if (tid < 32) {
                while (__hip_atomic_load(&flags[(rg << 5) + tid], __ATOMIC_RELAXED,
                                         __HIP_MEMORY_SCOPE_AGENT) < t)
                    __builtin_amdgcn_s_sleep(1);
            }
            __syncthreads();
        }
        // A fragments: agent-scope (cache-bypassing) loads of fresh h
        const u64* hrow = (const u64*)(hcur + (size_t)rowA * 512);
        short8 af[16];
        #pragma unroll
        for (int ks = 0; ks < 16; ks++) {
            union { u64 q[2]; short8 v; } uu;
            uu.q[0] = __hip_atomic_load(hrow + ks * 8 + quad * 2, __ATOMIC_RELAXED,
                                        __HIP_MEMORY_SCOPE_AGENT);
            uu.q[1] = __hip_atomic_load(hrow + ks * 8 + quad * 2 + 1, __ATOMIC_RELAXED,
                                        __HIP_MEMORY_SCOPE_AGENT);
            af[ks] = uu.v;
        }
        float4v acc[4] = {};
        #pragma unroll
        for (int ks = 0; ks < 16; ks++) {
            #pragma unroll
            for (int g = 0; g < 4; g++) {
                short8 bf = *(const short8*)&Ws[((g << 4) + mrow) * 520 + ks * 32 + quad * 8];
                acc[g] = __builtin_amdgcn_mfma_f32_16x16x32_bf16(af[ks], bf, acc[g], 0, 0, 0);
            }
        }
        // lane-local LSTM elementwise (i,f,g,o all in this lane)
        #pragma unroll
        for (int r = 0; r < 4; r++) {
            float ig = sigmoidf_(acc[0][r] + gb[0][r]);
            float fg = sigmoidf_(acc[1][r] + gb[1][r]);
            float gg = tanhf(acc[2][r] + gb[2][r]);
            float og = sigmoidf_(acc[3][r] + gb[3][r]);
            float cn = fg * cst[r] + ig * gg;
            cst[r] = cn;
            u16 hv = f2bf(og * tanhf(cn));
            // communicated state: agent-scope store (coherence point)
            __hip_atomic_store(&hnxt[(size_t)(rowC + r) * 512 + colh], hv,
                               __ATOMIC_RELAXED, __HIP_MEMORY_SCOPE_AGENT);
            // archive: plain cached store (flushed at kernel end)
            h_all[(size_t)(t * B_ + rowC + r) * 512 + colh] = hv;
        }
        // release: drain own stores, sync waves (compiler adds vmcnt(0) per
        // wave before s_barrier; explicit waitcnt belt-and-braces), set flag
        asm volatile("s_waitcnt vmcnt(0)" ::: "memory");
        __syncthreads();
        if (tid == 0)
            __hip_atomic_store(&flags[jb], t + 1, __ATOMIC_RELAXED,
                               __HIP_MEMORY_SCOPE_AGENT);
    }
}

// ---------------------------------------------------------------------------
// logits GEMM, 128x128 tile, BK=32, 4 waves each 64x64 (4x4 of 16x16x32).
// A = h_all [2560,512], B = cWo [VOCP,512] (zero-padded). C f32 -> d_out
// second half, col-guarded, + bo.
// ---------------------------------------------------------------------------
__global__ __launch_bounds__(256) void gemm128(const u16* __restrict__ A,
                                               const u16* __restrict__ Bm,
                                               const u16* __restrict__ biasbf,
                                               float* __restrict__ C) {
    __shared__ u16 As[128 * 32];
    __shared__ u16 Bs[128 * 32];
    int tid = threadIdx.x;
    int n0 = blockIdx.x * 128, m0 = blockIdx.y * 128;
    int w = tid >> 6, lane = tid & 63;
    int wm = (w & 1) * 64, wn = (w >> 1) * 64;
    int mrow = lane & 15, quad = lane >> 4;
    float4v acc[4][4] = {};
    for (int k0 = 0; k0 < 512; k0 += 32) {
        #pragma unroll
        for (int q = 0; q < 2; q++) {
            int idx = tid * 2 + q;              // 0..511 uint4s per matrix
            int r = idx >> 2, cc = (idx & 3) * 8;
            *(uint4*)&As[r * 32 + cc] = *(const uint4*)&A[(size_t)(m0 + r) * 512 + k0 + cc];
            *(uint4*)&Bs[r * 32 + cc] = *(const uint4*)&Bm[(size_t)(n0 + r) * 512 + k0 + cc];
        }
        __syncthreads();
        short8 af[4], bfv[4];
        #pragma unroll
        for (int i = 0; i < 4; i++)
            af[i] = *(const short8*)&As[(wm + i * 16 + mrow) * 32 + quad * 8];
        #pragma unroll
        for (int jn = 0; jn < 4; jn++)
            bfv[jn] = *(const short8*)&Bs[(wn + jn * 16 + mrow) * 32 + quad * 8];
        #pragma unroll
        for (int i = 0; i < 4; i++)
            #pragma unroll
            for (int jn = 0; jn < 4; jn++)
                acc[i][jn] = __builtin_amdgcn_mfma_f32_16x16x32_bf16(af[i], bfv[jn], acc[i][jn], 0, 0, 0);
        __syncthreads();
    }
    #pragma unroll
    for (int i = 0; i < 4; i++) {
        #pragma unroll
        for (int jn = 0; jn < 4; jn++) {
            int gcol = n0 + wn + jn * 16 + mrow;
            if (gcol >= VOC) continue;
            float bias = bf2f(biasbf[gcol]);
            #pragma unroll
            for (int r = 0; r < 4; r++) {
                int grow = m0 + wm + i * 16 + quad * 4 + r;
                C[(size_t)grow * VOC + gcol] = acc[i][jn][r] + bias;
            }
        }
    }
}

// ---------------------------------------------------------------------------
// fused log_softmax + softmax over d_out rows (f32). Raw logits in 2nd half.
// ---------------------------------------------------------------------------
__global__ __launch_bounds__(256) void softmax_out(float* __restrict__ out) {
    __shared__ float red[256];
    int r = blockIdx.x, tid = threadIdx.x;
    const size_t HALF4 = (size_t)T_ * B_ * VOC / 4;  // in float4 units
    float4* outv = (float4*)out;
    float4* src = outv + HALF4 + (size_t)r * (VOC / 4);
    float4 lv[10];
    float m = -1e30f;
    #pragma unroll
    for (int jq = 0; jq < 10; jq++) {
        int i4 = tid + jq * 256;
        if (i4 < VOC / 4) {
            float4 v = src[i4];
            lv[jq] = v;
            m = fmaxf(m, fmaxf(fmaxf(v.x, v.y), fmaxf(v.z, v.w)));
        } else {
            lv[jq] = make_float4(-1e30f, -1e30f, -1e30f, -1e30f);
        }
    }
    red[tid] = m; __syncthreads();
    for (int s = 128; s; s >>= 1) { if (tid < s) red[tid] = fmaxf(red[tid], red[tid + s]); __syncthreads(); }
    m = red[0]; __syncthreads();
    float sum = 0.f;
    #pragma unroll
    for (int jq = 0; jq < 10; jq++)
        sum += expf(lv[jq].x - m) + expf(lv[jq].y - m) + expf(lv[jq].z - m) + expf(lv[jq].w - m);
    red[tid] = sum; __syncthreads();
    for (int s = 128; s; s >>= 1) { if (tid < s) red[tid] += red[tid + s]; __syncthreads(); }
    float logZ = m + logf(red[0]);
    float4* dls = outv + (size_t)r * (VOC / 4);
    #pragma unroll
    for (int jq = 0; jq < 10; jq++) {
        int i4 = tid + jq * 256;
        if (i4 < VOC / 4) {
            float4 v = lv[jq];
            float4 ls = make_float4(v.x - logZ, v.y - logZ, v.z - logZ, v.w - logZ);
            dls[i4] = ls;
            src[i4] = make_float4(expf(ls.x), expf(ls.y), expf(ls.z), expf(ls.w));
        }
    }
}

extern "C" void kernel_launch(void* const* d_in, const int* in_sizes, int n_in,
                              void* d_out, int out_size, void* d_ws, size_t ws_size,
                              hipStream_t stream) {
    const float* features = (const float*)d_in[0];
    const int* captions   = (const int*)d_in[1];
    const float* W_init_h = (const float*)d_in[2];
    const float* W_init_c = (const float*)d_in[3];
    const float* Wv       = (const float*)d_in[4];
    // d_in[5] bv, d_in[6] Wa, d_in[7] ba unused (softmax shift-invariance)
    const float* embed_t  = (const float*)d_in[8];
    const float* W_ih     = (const float*)d_in[9];
    const float* W_hh     = (const float*)d_in[10];
    const float* b_ih     = (const float*)d_in[11];
    const float* b_hh     = (const float*)d_in[12];
    const float* Wo       = (const float*)d_in[13];
    const float* bo       = (const float*)d_in[14];
    float* out = (float*)d_out;

    // workspace layout (~43.5 MB)
    char* base = (char*)d_ws;
    int*   flags   = (int*)(base + 0);            // [64] barrier flags
    float* alpha   = (float*)(base + 1024);
    u16*   fbar_bf = (u16*)(base + 103424);
    u16*   ctx_bf  = (u16*)(base + 234496);
    u16*   h_pp    = (u16*)(base + 365568);       // 2 x 128*512 bf16
    float* c_f32   = (float*)(base + 627712);
    float* gconst  = (float*)(base + 889856);     // [128,2048] f32
    u16*   Ebf     = (u16*)(base + 1938432);      // [2560,256] bf16
    float* gbase   = (float*)(base + 3249152);    // [2560,2048] f32
    u16*   h_all   = (u16*)(base + 24220672);     // [2560,512] bf16
    u16*   cWih    = (u16*)(base + 26842112);     // [2048,768] bf16
    u16*   cWhh    = (u16*)(base + 29987840);     // [2048,512]
    u16*   cWo     = (u16*)(base + 32084992);     // [VOCP,512] padded
    u16*   cWinit  = (u16*)(base + 42439680);     // [1024,512] (Winh;Winc)
    u16*   cbih    = (u16*)(base + 43488256);
    u16*   cbhh    = (u16*)(base + 43492352);
    u16*   cbo     = (u16*)(base + 43496448);     // [VOCP] padded

    // 1) weight conversion (+ flag zero)
    conv_all<<<32568, 256, 0, stream>>>(W_ih, W_hh, Wo, W_init_h, W_init_c,
                                        b_ih, b_hh, bo,
                                        cWih, cWhh, cWo, cWinit, cbih, cbhh, cbo, flags);
    // 2) attention weights + context/mean features
    att_kernel<<<B_, 256, 0, stream>>>(features, Wv, alpha);
    ctx_fbar<<<dim3(2, B_), 256, 0, stream>>>(features, alpha, fbar_bf, ctx_bf);
    // 3) embeddings (time-major)
    gather_emb<<<T_ * B_, 256, 0, stream>>>(captions, embed_t, Ebf);
    // 4) h0 | c0 = fbar @ [Winh; Winc]^T   (split epilogue)
    gemm_bt<<<dim3(16, 2), 256, 0, stream>>>(
        fbar_bf, 512, cWinit, 512, B_, 1024, 512,
        nullptr, nullptr, nullptr, -1, c_f32, h_pp, 1024, 2);
    // 5) gconst = ctx @ W_ih[:, :512]^T + b_ih + b_hh   [128,2048] f32
    gemm_bt<<<dim3(32, 2), 256, 0, stream>>>(
        ctx_bf, 512, cWih, 768, B_, 2048, 512,
        cbih, cbhh, nullptr, -1, gconst, nullptr, 2048, 1);
    // 6) gbase = E @ W_ih[:, 512:768]^T + gconst[b]   [2560,2048] f32
    gemm_bt<<<dim3(32, 40), 256, 0, stream>>>(
        Ebf, 256, cWih + 512, 768, T_ * B_, 2048, 256,
        nullptr, nullptr, gconst, 127, gbase, nullptr, 2048, 1);
    // 7) fused 20-step LSTM recurrence (single persistent launch)
    recurrence<<<NBLK, 256, 0, stream>>>(cWhh, gbase, c_f32, h_pp, h_all, flags);
    // 8) logits = h_all @ Wo^T + bo -> f32 raw into d_out's second half
    gemm128<<<dim3(VOCP / 128, (T_ * B_) / 128), 256, 0, stream>>>(
        h_all, cWo, cbo, out + (size_t)T_ * B_ * VOC);
    // 9) fused log_softmax + softmax in place
    softmax_out<<<T_ * B_, 256, 0, stream>>>(out);
}

// Round 3
// 583.758 us; speedup vs baseline: 1.3288x; 1.0520x over previous
//
#include <hip/hip_runtime.h>

typedef unsigned short u16;
typedef unsigned int u32;
typedef unsigned long long u64;

typedef __attribute__((ext_vector_type(8))) short short8;
typedef __attribute__((ext_vector_type(4))) float float4v;

__device__ __forceinline__ float bf2f(u16 u) { return __uint_as_float(((u32)u) << 16); }
__device__ __forceinline__ u16 f2bf(float f) {
    u32 x = __float_as_uint(f);
    return (u16)((x + 0x7fffu + ((x >> 16) & 1u)) >> 16);
}
__device__ __forceinline__ float sigmoidf_(float x) { return 1.0f / (1.0f + expf(-x)); }

#define B_ 128
#define T_ 20
#define VISN 196
#define VISD 512
#define EMB 256
#define HID 512
#define VOC 10000
#define VOCP 10112   /* padded to 79*128 */
#define NBLK 64      /* recurrence grid: 2 rowgroups x 32 colgroups */

// fragment-major h layout: element (strip, ks, quad, mrow, e) at u16 offset
//   F = (((strip*16 + ks)*4 + quad)*16 + mrow)*8 + e
// strip = row>>4, mrow = row&15, ks = k>>5, quad = (k>>3)&3, e = k&7.
// A wave's af[ks] fragment is then one contiguous 1KB burst.

// ---------------------------------------------------------------------------
// fused weight conversion f32 -> bf16 (+ zero-pad Wo/bo to VOCP, zero flags)
// ---------------------------------------------------------------------------
__global__ __launch_bounds__(256) void conv_all(
    const float* __restrict__ Wih, const float* __restrict__ Whh,
    const float* __restrict__ Wo,  const float* __restrict__ Winh,
    const float* __restrict__ Winc, const float* __restrict__ bih,
    const float* __restrict__ bhh, const float* __restrict__ bo,
    u16* __restrict__ cWih, u16* __restrict__ cWhh, u16* __restrict__ cWo,
    u16* __restrict__ cWinit, u16* __restrict__ cbih, u16* __restrict__ cbhh,
    u16* __restrict__ cbo, int* __restrict__ flags) {
    const int e0 = 1572864, e1 = 2621440, e2 = 7798784, e3 = 8060928,
              e4 = 8323072, e5 = 8325120, e6 = 8327168, e7 = 8337280;
    int gid = blockIdx.x * 256 + threadIdx.x;
    if (gid < 256) flags[gid] = 0;     // 1KB flag region (line-transposed idx)
    if (gid >= e7) return;
    if (gid < e0) { cWih[gid] = f2bf(Wih[gid]); }
    else if (gid < e1) { int l = gid - e0; cWhh[l] = f2bf(Whh[l]); }
    else if (gid < e2) {
        int l = gid - e1; int row = l >> 9, col = l & 511;
        cWo[l] = (row < VOC) ? f2bf(Wo[(size_t)row * 512 + col]) : (u16)0;
    }
    else if (gid < e3) { int l = gid - e2; cWinit[l] = f2bf(Winh[l]); }
    else if (gid < e4) { int l = gid - e3; cWinit[262144 + l] = f2bf(Winc[l]); }
    else if (gid < e5) { int l = gid - e4; cbih[l] = f2bf(bih[l]); }
    else if (gid < e6) { int l = gid - e5; cbhh[l] = f2bf(bhh[l]); }
    else { int l = gid - e6; cbo[l] = (l < VOC) ? f2bf(bo[l]) : (u16)0; }
}

// ---------------------------------------------------------------------------
// att: alpha[b,n] = softmax_n(features[b,n,:]·Wv). h-term of the logit is
// constant over n -> softmax-invariant -> dropped. One block per b.
// ---------------------------------------------------------------------------
__global__ __launch_bounds__(256) void att_kernel(const float* __restrict__ feat,
                                                  const float* __restrict__ Wv,
                                                  float* __restrict__ alpha) {
    __shared__ float wv[512];
    __shared__ float att[VISN];
    __shared__ float red[256];
    int b = blockIdx.x, tid = threadIdx.x;
    wv[tid] = Wv[tid];
    wv[tid + 256] = Wv[tid + 256];
    __syncthreads();
    int w = tid >> 6, lane = tid & 63;
    for (int n = w; n < VISN; n += 4) {
        const float4* fp = (const float4*)(feat + ((size_t)b * VISN + n) * VISD) + lane * 2;
        float4 a = fp[0], c = fp[1];
        const float* wp = wv + lane * 8;
        float s = a.x * wp[0] + a.y * wp[1] + a.z * wp[2] + a.w * wp[3]
                + c.x * wp[4] + c.y * wp[5] + c.z * wp[6] + c.w * wp[7];
        #pragma unroll
        for (int off = 32; off; off >>= 1) s += __shfl_down(s, off);
        if (lane == 0) att[n] = s;
    }
    __syncthreads();
    float m = -1e30f;
    for (int i = tid; i < VISN; i += 256) m = fmaxf(m, att[i]);
    red[tid] = m; __syncthreads();
    for (int s = 128; s; s >>= 1) { if (tid < s) red[tid] = fmaxf(red[tid], red[tid + s]); __syncthreads(); }
    m = red[0]; __syncthreads();
    float sum = 0.f;
    for (int i = tid; i < VISN; i += 256) { float e = expf(att[i] - m); att[i] = e; sum += e; }
    red[tid] = sum; __syncthreads();
    for (int s = 128; s; s >>= 1) { if (tid < s) red[tid] += red[tid + s]; __syncthreads(); }
    float inv = 1.0f / red[0]; __syncthreads();
    for (int i = tid; i < VISN; i += 256) alpha[b * VISN + i] = att[i] * inv;
}

// ---------------------------------------------------------------------------
// ctx/fbar: fbar = mean_n feat, ctx = sum_n alpha*feat. grid (2 vslices, 128 b)
// ---------------------------------------------------------------------------
__global__ __launch_bounds__(256) void ctx_fbar(const float* __restrict__ feat,
                                                const float* __restrict__ alpha,
                                                u16* __restrict__ fbar_bf,
                                                u16* __restrict__ ctx_bf) {
    __shared__ float al[VISN];
    int b = blockIdx.y, tid = threadIdx.x;
    int v = blockIdx.x * 256 + tid;
    if (tid < VISN) al[tid] = alpha[b * VISN + tid];
    __syncthreads();
    float accf = 0.f, accc = 0.f;
    const float* fp = feat + (size_t)b * VISN * VISD + v;
    #pragma unroll 4
    for (int n = 0; n < VISN; n++) {
        float f = fp[(size_t)n * VISD];
        accf += f;
        accc += al[n] * f;
    }
    fbar_bf[b * VISD + v] = f2bf(accf / (float)VISN);
    ctx_bf[b * VISD + v] = f2bf(accc);
}

// gather embeddings, time-major r = t*B + b
__global__ void gather_emb(const int* __restrict__ captions, const float* __restrict__ table,
                           u16* __restrict__ Ebf) {
    int r = blockIdx.x;
    int t = r >> 7, b = r & 127;
    int idx = captions[b * T_ + t];
    Ebf[(size_t)r * EMB + threadIdx.x] = f2bf(table[(size_t)idx * EMB + threadIdx.x]);
}

// ---------------------------------------------------------------------------
// bf16 MFMA GEMM, 64x64 tile, BK=32. C = A[M,K]·B[N,K]^T + biases + addA.
// mode 0: write bf16 Cbf; mode 1: write f32 Cf; mode 2: h0c0 split
// (col<512 -> Cbf = h0 in FRAGMENT layout, else Cf = c f32 row-major).
// addA (f32) indexed [(grow & rowmask)*ldc + gcol].
// ---------------------------------------------------------------------------
__global__ __launch_bounds__(256) void gemm_bt(const u16* __restrict__ A, int lda,
                                               const u16* __restrict__ Bm, int ldb,
                                               int M, int N, int K,
                                               const u16* __restrict__ bias0,
                                               const u16* __restrict__ bias1,
                                               const float* __restrict__ addA, int rowmask,
                                               float* __restrict__ Cf,
                                               u16* __restrict__ Cbf, int ldc, int mode) {
    __shared__ u16 As[64 * 32];
    __shared__ u16 Bs[64 * 32];
    int tid = threadIdx.x;
    int n0 = blockIdx.x * 64, m0 = blockIdx.y * 64;
    int w = tid >> 6, lane = tid & 63;
    int wm = (w & 1) * 32, wn = (w >> 1) * 32;
    int mrow = lane & 15, quad = lane >> 4;
    float4v acc[2][2] = {};
    int lr = tid >> 2;
    int lc = (tid & 3) * 8;
    for (int k0 = 0; k0 < K; k0 += 32) {
        *(uint4*)(&As[lr * 32 + lc]) = *(const uint4*)(A + (size_t)(m0 + lr) * lda + k0 + lc);
        *(uint4*)(&Bs[lr * 32 + lc]) = *(const uint4*)(Bm + (size_t)(n0 + lr) * ldb + k0 + lc);
        __syncthreads();
        short8 afrag[2], bfrag[2];
        #pragma unroll
        for (int i = 0; i < 2; i++)
            afrag[i] = *(const short8*)(&As[(wm + i * 16 + mrow) * 32 + quad * 8]);
        #pragma unroll
        for (int j = 0; j < 2; j++)
            bfrag[j] = *(const short8*)(&Bs[(wn + j * 16 + mrow) * 32 + quad * 8]);
        #pragma unroll
        for (int i = 0; i < 2; i++)
            #pragma unroll
            for (int j = 0; j < 2; j++)
                acc[i][j] = __builtin_amdgcn_mfma_f32_16x16x32_bf16(afrag[i], bfrag[j], acc[i][j], 0, 0, 0);
        __syncthreads();
    }
    #pragma unroll
    for (int i = 0; i < 2; i++) {
        #pragma unroll
        for (int j = 0; j < 2; j++) {
            #pragma unroll
            for (int r = 0; r < 4; r++) {
                int grow = m0 + wm + i * 16 + quad * 4 + r;
                int gcol = n0 + wn + j * 16 + mrow;
                float v = acc[i][j][r];
                if (bias0) v += bf2f(bias0[gcol]);
                if (bias1) v += bf2f(bias1[gcol]);
                if (addA) v += addA[(size_t)(grow & rowmask) * ldc + gcol];
                if (mode == 0) {
                    Cbf[(size_t)grow * ldc + gcol] = f2bf(v);
                } else if (mode == 1) {
                    Cf[(size_t)grow * ldc + gcol] = v;
                } else {  // mode 2: h0 (fragment layout) / c0 split
                    if (gcol < 512) {
                        size_t o = ((((size_t)(grow >> 4) * 16 + (gcol >> 5)) * 4 +
                                     ((gcol >> 3) & 3)) * 16 + (grow & 15)) * 8 + (gcol & 7);
                        Cbf[o] = f2bf(v);
                    } else {
                        Cf[(size_t)grow * 512 + gcol - 512] = v;
                    }
                }
            }
        }
    }
}

// ---------------------------------------------------------------------------
// persistent fused recurrence, v4: 64 blocks = 2 rowgroups x 32 colgroups.
// v3 -> v4:
//   - B-fragments (W_hh slice) hoisted to REGISTERS once (256 VGPRs/lane):
//     kills the 4x-redundant 256 ds_read_b128/CU/step + 1.3M bank conflicts
//   - h ping-pong in MFMA-FRAGMENT-major layout: a wave's af[ks] is one
//     contiguous 1KB burst (was 8B x 1KB-stride scatter, 8x overfetch)
//   - producer stages its 64x16 output tile in a 2KB LDS exchange buffer,
//     then emits coalesced dword stores (frag) + 16B-chunk stores (h_all)
//     instead of 1024 scattered 2B stores -> faster vmcnt drain
//   - flags line-transposed: fi = ((jb&15)<<4)|(jb>>4) spreads the 32 polled
//     flags of a rowgroup over 16 cache lines
// Sync protocol unchanged from v3 (relaxed agent-scope ops at the coherence
// point; release = vmcnt(0) + flag store; acquire = flag poll; buffer parity
// guarantees no ping-pong race).
// ---------------------------------------------------------------------------
__global__ __launch_bounds__(256, 1) void recurrence(
    const u16* __restrict__ Whh,      // [2048,512] bf16
    const float* __restrict__ gbase,  // [2560,2048] f32 (row = t*128+b)
    const float* __restrict__ c0,     // [128,512] f32
    u16* __restrict__ h_pp,           // [2][65536] bf16 FRAGMENT layout, buf0 = h0
    u16* __restrict__ h_all,          // [2560,512] bf16 row-major
    int* __restrict__ flags) {        // 256 ints, line-transposed indexing
    __shared__ u16 Ws[64 * 520];                  // staging for W_hh slice
    __shared__ __align__(16) u16 ex[64 * 16];     // output exchange tile
    int jb = blockIdx.x, tid = threadIdx.x;
    int rg = jb >> 5, cg = jb & 31;
    // stage W_hh slice: local row lcol = g*16+q -> global row g*512+16*cg+q
    for (int idx = tid; idx < 64 * 64; idx += 256) {
        int lcol = idx >> 6, q8 = idx & 63;
        int grow = ((lcol >> 4) << 9) + (cg << 4) + (lcol & 15);
        *(uint4*)&Ws[lcol * 520 + q8 * 8] = *(const uint4*)&Whh[(size_t)grow * 512 + q8 * 8];
    }
    int w = tid >> 6, lane = tid & 63;
    int mrow = lane & 15, quad = lane >> 4;
    int rowC = (rg << 6) + (w << 4) + (quad << 2);   // C row base (+r)
    int strip = (rg << 2) + w;                       // h-fragment strip
    int colh = (cg << 4) + mrow;                     // owned h column
    float cst[4];
    #pragma unroll
    for (int r = 0; r < 4; r++) cst[r] = c0[(size_t)(rowC + r) * 512 + colh];
    __syncthreads();
    // one-time: ALL 64 B-fragments to registers (time-invariant weights)
    short8 bfv[16][4];
    #pragma unroll
    for (int ks = 0; ks < 16; ks++)
        #pragma unroll
        for (int g = 0; g < 4; g++)
            bfv[ks][g] = *(const short8*)&Ws[((g << 4) + mrow) * 520 + ks * 32 + quad * 8];
    for (int t = 0; t < T_; t++) {
        const u64* hb64 = (const u64*)(h_pp + (t & 1) * 65536);
        u16* hnxt = h_pp + ((t + 1) & 1) * 65536;
        // gbase addends for THIS step: plain cached loads, issued before the
        // poll so they drain under the barrier wait
        float gb[4][4];
        #pragma unroll
        for (int g = 0; g < 4; g++)
            #pragma unroll
            for (int r = 0; r < 4; r++)
                gb[g][r] = gbase[(size_t)(t * B_ + rowC + r) * 2048 + (g << 9) + colh];
        // barrier-at-head: wait for all rowgroup peers to release step t
        if (t > 0) {
            if (tid < 32) {
                int pj = (rg << 5) + tid;
                int fi = ((pj & 15) << 4) + (pj >> 4);
                while (__hip_atomic_load(&flags[fi], __ATOMIC_RELAXED,
                                         __HIP_MEMORY_SCOPE_AGENT) < t)
                    __builtin_amdgcn_s_sleep(1);
            }
            __syncthreads();
        }
        // A fragments: coalesced agent-scope loads from fragment-major h
        short8 af[16];
        #pragma unroll
        for (int ks = 0; ks < 16; ks++) {
            int o = (((strip * 16 + ks) * 4 + quad) * 16 + mrow) * 2;  // u64 idx
            union { u64 q[2]; short8 v; } uu;
            uu.q[0] = __hip_atomic_load(hb64 + o, __ATOMIC_RELAXED,
                                        __HIP_MEMORY_SCOPE_AGENT);
            uu.q[1] = __hip_atomic_load(hb64 + o + 1, __ATOMIC_RELAXED,
                                        __HIP_MEMORY_SCOPE_AGENT);
            af[ks] = uu.v;
        }
        float4v acc[4] = {};
        #pragma unroll
        for (int ks = 0; ks < 16; ks++)
            #pragma unroll
            for (int g = 0; g < 4; g++)
                acc[g] = __builtin_amdgcn_mfma_f32_16x16x32_bf16(af[ks], bfv[ks][g], acc[g], 0, 0, 0);
        // lane-local LSTM elementwise -> exchange tile (local [64][16])
        #pragma unroll
        for (int r = 0; r < 4; r++) {
            float ig = sigmoidf_(acc[0][r] + gb[0][r]);
            float fg = sigmoidf_(acc[1][r] + gb[1][r]);
            float gg = tanhf(acc[2][r] + gb[2][r]);
            float og = sigmoidf_(acc[3][r] + gb[3][r]);
            float cn = fg * cst[r] + ig * gg;
            cst[r] = cn;
            ex[((w << 4) + (quad << 2) + r) * 16 + mrow] = f2bf(og * tanhf(cn));
        }
        __syncthreads();
        // coalesced emit: fragment-layout h (agent-scope dwords) ...
        const u32* ex32 = (const u32*)ex;
        #pragma unroll
        for (int h2 = 0; h2 < 2; h2++) {
            int d = tid + h2 * 256;
            int c = d >> 6, i = d & 63;
            int wl = c >> 1, qs = c & 1, mw = i >> 2, ep = i & 3;
            u32 val = ex32[((wl * 16 + mw) * 16 + qs * 8 + ep * 2) >> 1];
            size_t o16 = ((((size_t)((rg << 2) + wl) * 16 + (cg >> 1)) * 4 +
                          ((cg & 1) * 2 + qs)) * 16 + mw) * 8 + ep * 2;
            __hip_atomic_store((u32*)hnxt + (o16 >> 1), val,
                               __ATOMIC_RELAXED, __HIP_MEMORY_SCOPE_AGENT);
        }
        // ... and row-major h_all (16B chunks, plain cached)
        if (tid < 128) {
            int rl = tid >> 1, hf = tid & 1;
            uint4 v = *(const uint4*)&ex[rl * 16 + hf * 8];
            *(uint4*)&h_all[(size_t)(t * B_ + (rg << 6) + rl) * 512 + (cg << 4) + hf * 8] = v;
        }
        // release: drain stores, sync waves, set flag
        asm volatile("s_waitcnt vmcnt(0)" ::: "memory");
        __syncthreads();
        if (tid == 0) {
            int fi = ((jb & 15) << 4) + (jb >> 4);
            __hip_atomic_store(&flags[fi], t + 1, __ATOMIC_RELAXED,
                               __HIP_MEMORY_SCOPE_AGENT);
        }
    }
}

// ---------------------------------------------------------------------------
// logits GEMM, 128x128 tile, BK=32, 4 waves each 64x64 (4x4 of 16x16x32).
// A = h_all [2560,512], B = cWo [VOCP,512] (zero-padded). C f32 -> d_out
// second half, col-guarded, + bo.
// ---------------------------------------------------------------------------
__global__ __launch_bounds__(256) void gemm128(const u16* __restrict__ A,
                                               const u16* __restrict__ Bm,
                                               const u16* __restrict__ biasbf,
                                               float* __restrict__ C) {
    __shared__ u16 As[128 * 32];
    __shared__ u16 Bs[128 * 32];
    int tid = threadIdx.x;
    int n0 = blockIdx.x * 128, m0 = blockIdx.y * 128;
    int w = tid >> 6, lane = tid & 63;
    int wm = (w & 1) * 64, wn = (w >> 1) * 64;
    int mrow = lane & 15, quad = lane >> 4;
    float4v acc[4][4] = {};
    for (int k0 = 0; k0 < 512; k0 += 32) {
        #pragma unroll
        for (int q = 0; q < 2; q++) {
            int idx = tid * 2 + q;              // 0..511 uint4s per matrix
            int r = idx >> 2, cc = (idx & 3) * 8;
            *(uint4*)&As[r * 32 + cc] = *(const uint4*)&A[(size_t)(m0 + r) * 512 + k0 + cc];
            *(uint4*)&Bs[r * 32 + cc] = *(const uint4*)&Bm[(size_t)(n0 + r) * 512 + k0 + cc];
        }
        __syncthreads();
        short8 af[4], bfv[4];
        #pragma unroll
        for (int i = 0; i < 4; i++)
            af[i] = *(const short8*)&As[(wm + i * 16 + mrow) * 32 + quad * 8];
        #pragma unroll
        for (int jn = 0; jn < 4; jn++)
            bfv[jn] = *(const short8*)&Bs[(wn + jn * 16 + mrow) * 32 + quad * 8];
        #pragma unroll
        for (int i = 0; i < 4; i++)
            #pragma unroll
            for (int jn = 0; jn < 4; jn++)
                acc[i][jn] = __builtin_amdgcn_mfma_f32_16x16x32_bf16(af[i], bfv[jn], acc[i][jn], 0, 0, 0);
        __syncthreads();
    }
    #pragma unroll
    for (int i = 0; i < 4; i++) {
        #pragma unroll
        for (int jn = 0; jn < 4; jn++) {
            int gcol = n0 + wn + jn * 16 + mrow;
            if (gcol >= VOC) continue;
            float bias = bf2f(biasbf[gcol]);
            #pragma unroll
            for (int r = 0; r < 4; r++) {
                int grow = m0 + wm + i * 16 + quad * 4 + r;
                C[(size_t)grow * VOC + gcol] = acc[i][jn][r] + bias;
            }
        }
    }
}

// ---------------------------------------------------------------------------
// fused log_softmax + softmax over d_out rows (f32). Raw logits in 2nd half.
// ---------------------------------------------------------------------------
__global__ __launch_bounds__(256) void softmax_out(float* __restrict__ out) {
    __shared__ float red[256];
    int r = blockIdx.x, tid = threadIdx.x;
    const size_t HALF4 = (size_t)T_ * B_ * VOC / 4;  // in float4 units
    float4* outv = (float4*)out;
    float4* src = outv + HALF4 + (size_t)r * (VOC / 4);
    float4 lv[10];
    float m = -1e30f;
    #pragma unroll
    for (int jq = 0; jq < 10; jq++) {
        int i4 = tid + jq * 256;
        if (i4 < VOC / 4) {
            float4 v = src[i4];
            lv[jq] = v;
            m = fmaxf(m, fmaxf(fmaxf(v.x, v.y), fmaxf(v.z, v.w)));
        } else {
            lv[jq] = make_float4(-1e30f, -1e30f, -1e30f, -1e30f);
        }
    }
    red[tid] = m; __syncthreads();
    for (int s = 128; s; s >>= 1) { if (tid < s) red[tid] = fmaxf(red[tid], red[tid + s]); __syncthreads(); }
    m = red[0]; __syncthreads();
    float sum = 0.f;
    #pragma unroll
    for (int jq = 0; jq < 10; jq++)
        sum += expf(lv[jq].x - m) + expf(lv[jq].y - m) + expf(lv[jq].z - m) + expf(lv[jq].w - m);
    red[tid] = sum; __syncthreads();
    for (int s = 128; s; s >>= 1) { if (tid < s) red[tid] += red[tid + s]; __syncthreads(); }
    float logZ = m + logf(red[0]);
    float4* dls = outv + (size_t)r * (VOC / 4);
    #pragma unroll
    for (int jq = 0; jq < 10; jq++) {
        int i4 = tid + jq * 256;
        if (i4 < VOC / 4) {
            float4 v = lv[jq];
            float4 ls = make_float4(v.x - logZ, v.y - logZ, v.z - logZ, v.w - logZ);
            dls[i4] = ls;
            src[i4] = make_float4(expf(ls.x), expf(ls.y), expf(ls.z), expf(ls.w));
        }
    }
}

extern "C" void kernel_launch(void* const* d_in, const int* in_sizes, int n_in,
                              void* d_out, int out_size, void* d_ws, size_t ws_size,
                              hipStream_t stream) {
    const float* features = (const float*)d_in[0];
    const int* captions   = (const int*)d_in[1];
    const float* W_init_h = (const float*)d_in[2];
    const float* W_init_c = (const float*)d_in[3];
    const float* Wv       = (const float*)d_in[4];
    // d_in[5] bv, d_in[6] Wa, d_in[7] ba unused (softmax shift-invariance)
    const float* embed_t  = (const float*)d_in[8];
    const float* W_ih     = (const float*)d_in[9];
    const float* W_hh     = (const float*)d_in[10];
    const float* b_ih     = (const float*)d_in[11];
    const float* b_hh     = (const float*)d_in[12];
    const float* Wo       = (const float*)d_in[13];
    const float* bo       = (const float*)d_in[14];
    float* out = (float*)d_out;

    // workspace layout (~43.5 MB)
    char* base = (char*)d_ws;
    int*   flags   = (int*)(base + 0);            // 1KB, line-transposed flags
    float* alpha   = (float*)(base + 1024);
    u16*   fbar_bf = (u16*)(base + 103424);
    u16*   ctx_bf  = (u16*)(base + 234496);
    u16*   h_pp    = (u16*)(base + 365568);       // 2 x 65536 bf16 (fragment)
    float* c_f32   = (float*)(base + 627712);
    float* gconst  = (float*)(base + 889856);     // [128,2048] f32
    u16*   Ebf     = (u16*)(base + 1938432);      // [2560,256] bf16
    float* gbase   = (float*)(base + 3249152);    // [2560,2048] f32
    u16*   h_all   = (u16*)(base + 24220672);     // [2560,512] bf16
    u16*   cWih    = (u16*)(base + 26842112);     // [2048,768] bf16
    u16*   cWhh    = (u16*)(base + 29987840);     // [2048,512]
    u16*   cWo     = (u16*)(base + 32084992);     // [VOCP,512] padded
    u16*   cWinit  = (u16*)(base + 42439680);     // [1024,512] (Winh;Winc)
    u16*   cbih    = (u16*)(base + 43488256);
    u16*   cbhh    = (u16*)(base + 43492352);
    u16*   cbo     = (u16*)(base + 43496448);     // [VOCP] padded

    // 1) weight conversion (+ flag zero)
    conv_all<<<32568, 256, 0, stream>>>(W_ih, W_hh, Wo, W_init_h, W_init_c,
                                        b_ih, b_hh, bo,
                                        cWih, cWhh, cWo, cWinit, cbih, cbhh, cbo, flags);
    // 2) attention weights + context/mean features
    att_kernel<<<B_, 256, 0, stream>>>(features, Wv, alpha);
    ctx_fbar<<<dim3(2, B_), 256, 0, stream>>>(features, alpha, fbar_bf, ctx_bf);
    // 3) embeddings (time-major)
    gather_emb<<<T_ * B_, 256, 0, stream>>>(captions, embed_t, Ebf);
    // 4) h0 (fragment layout) | c0 = fbar @ [Winh; Winc]^T (split epilogue)
    gemm_bt<<<dim3(16, 2), 256, 0, stream>>>(
        fbar_bf, 512, cWinit, 512, B_, 1024, 512,
        nullptr, nullptr, nullptr, -1, c_f32, h_pp, 1024, 2);
    // 5) gconst = ctx @ W_ih[:, :512]^T + b_ih + b_hh   [128,2048] f32
    gemm_bt<<<dim3(32, 2), 256, 0, stream>>>(
        ctx_bf, 512, cWih, 768, B_, 2048, 512,
        cbih, cbhh, nullptr, -1, gconst, nullptr, 2048, 1);
    // 6) gbase = E @ W_ih[:, 512:768]^T + gconst[b]   [2560,2048] f32
    gemm_bt<<<dim3(32, 40), 256, 0, stream>>>(
        Ebf, 256, cWih + 512, 768, T_ * B_, 2048, 256,
        nullptr, nullptr, gconst, 127, gbase, nullptr, 2048, 1);
    // 7) fused 20-step LSTM recurrence (single persistent launch)
    recurrence<<<NBLK, 256, 0, stream>>>(cWhh, gbase, c_f32, h_pp, h_all, flags);
    // 8) logits = h_all @ Wo^T + bo -> f32 raw into d_out's second half
    gemm128<<<dim3(VOCP / 128, (T_ * B_) / 128), 256, 0, stream>>>(
        h_all, cWo, cbo, out + (size_t)T_ * B_ * VOC);
    // 9) fused log_softmax + softmax in place
    softmax_out<<<T_ * B_, 256, 0, stream>>>(out);
}